// Round 2
// baseline (775.446 us; speedup 1.0000x reference)
//
#include <hip/hip_runtime.h>

// CrossAttention: out = softmax((S2 Wq)(S1 Wk)^T) (S1 Wv) Wo + bo
// Refactored: Wvo = Wv@Wo;  V'' = S1@Wvo + bo;  out = softmax(QK^T) @ V''
// R8: back to R6's proven shapes (512-thr blocks, Q-tile 128, vf[4] PV, no
// spill) but the QK^T phase is now BARRIER-FREE: Q and K fragments are loaded
// per-wave directly from global (A/B-frag = 8 contiguous halves at
// [row=l16][ks*32+q16*8], same pattern PV already uses for V). This removes
// all 128 stage->vmcnt(0)->barrier drains of R6/R7; only 2 barriers per kt
// remain (Ps cross-wave handoff). LDS = Ps+arow only (35 KB). L1 (32 KB)
// filters the 8-wave K re-read; occupancy stays register-capped at 8 waves/CU.

typedef _Float16 h_t;
typedef _Float16 h8 __attribute__((ext_vector_type(8)));
typedef _Float16 h4 __attribute__((ext_vector_type(4)));
typedef float f4 __attribute__((ext_vector_type(4)));

#define MFMA16(a, b, c) __builtin_amdgcn_mfma_f32_16x16x32_f16(a, b, c, 0, 0, 0)

typedef const __attribute__((address_space(1))) void* gas_t;
typedef __attribute__((address_space(3))) void* las_t;

__device__ __forceinline__ void gl2lds16(const void* g, void* l) {
    __builtin_amdgcn_global_load_lds((gas_t)g, (las_t)l, 16, 0, 0);
}

// ---------------- merged cast fp32 -> fp16: S1, S2, Wv ----------------
__global__ __launch_bounds__(256) void k_cast3(const float* __restrict__ S1,
                                               const float* __restrict__ S2,
                                               const float* __restrict__ Wv,
                                               h_t* __restrict__ S1h,
                                               h_t* __restrict__ S2h,
                                               h_t* __restrict__ Wvh) {
    long i = (long)blockIdx.x * 256 + threadIdx.x;  // f4 index
    const long n = 2097152;                          // S1/S2 f4 count
    const float* src;
    h_t* dst;
    long off;
    if (i < n) { src = S1; dst = S1h; off = i; }
    else if (i < 2 * n) { src = S2; dst = S2h; off = i - n; }
    else { src = Wv; dst = Wvh; off = i - 2 * n; }
    float4 v = *((const float4*)src + off);
    h4 h = {(h_t)v.x, (h_t)v.y, (h_t)v.z, (h_t)v.w};
    *((h4*)dst + off) = h;
}

// ---------------- merged transpose+cast: Wq, Wk, Wo -> [N][K] f16 ----------------
__global__ __launch_bounds__(256) void k_transpose3(const float* __restrict__ Wq,
                                                    const float* __restrict__ Wk,
                                                    const float* __restrict__ Wo,
                                                    h_t* __restrict__ Wqt,
                                                    h_t* __restrict__ Wkt,
                                                    h_t* __restrict__ Wot) {
    const float* in;
    h_t* out;
    int K, N;
    if (blockIdx.z == 0) { in = Wq; out = Wqt; K = 512; N = 1024; }
    else if (blockIdx.z == 1) { in = Wk; out = Wkt; K = 512; N = 1024; }
    else { in = Wo; out = Wot; K = 1024; N = 512; }
    int kb = blockIdx.y * 32, nb = blockIdx.x * 32;
    if (kb >= K || nb >= N) return;
    __shared__ float tile[32][33];
    int x = threadIdx.x & 31, y = threadIdx.x >> 5;
#pragma unroll
    for (int j = 0; j < 4; j++)
        tile[y + j * 8][x] = in[(size_t)(kb + y + j * 8) * N + nb + x];
    __syncthreads();
#pragma unroll
    for (int j = 0; j < 4; j++)
        out[(size_t)(nb + y + j * 8) * K + kb + x] = (h_t)tile[x][y + j * 8];
}

// ---------------- m97-style NT GEMM: C[M][N] f16 = A[M][K] x Bt[N][K]^T ------------
__global__ __launch_bounds__(256) void k_gemm(const h_t* __restrict__ A,
                                              const h_t* __restrict__ Bt,
                                              h_t* __restrict__ C,
                                              int M, int N, int K) {
    __shared__ h_t As[128 * 64];
    __shared__ h_t Bs[128 * 64];
    int t = threadIdx.x, w = t >> 6, lane = t & 63;
    int q16 = lane >> 4, l16 = lane & 15;
    size_t m0 = (size_t)blockIdx.x * 128, n0 = (size_t)blockIdx.y * 128;
    int wr = (w >> 1) * 64, wc = (w & 1) * 64;
    f4 acc[4][4] = {};

    for (int k0 = 0; k0 < K; k0 += 64) {
#pragma unroll
        for (int j = 0; j < 4; j++) {
            int q = w * 4 + j;
            int row = q * 8 + (lane >> 3);
            int ks = (((lane & 7) ^ (row & 7)) << 3);
            gl2lds16(A + (m0 + row) * K + k0 + ks, &As[q * 512]);
            gl2lds16(Bt + (n0 + row) * K + k0 + ks, &Bs[q * 512]);
        }
        __syncthreads();
#pragma unroll
        for (int ks = 0; ks < 2; ks++) {
            h8 av[4], bv[4];
#pragma unroll
            for (int i = 0; i < 4; i++) {
                int row = wr + i * 16 + l16;
                int ch = ks * 4 + q16;
                av[i] = *(const h8*)&As[row * 64 + ((ch ^ (row & 7)) << 3)];
            }
#pragma unroll
            for (int j = 0; j < 4; j++) {
                int row = wc + j * 16 + l16;
                int ch = ks * 4 + q16;
                bv[j] = *(const h8*)&Bs[row * 64 + ((ch ^ (row & 7)) << 3)];
            }
#pragma unroll
            for (int i = 0; i < 4; i++)
#pragma unroll
                for (int j = 0; j < 4; j++)
                    acc[i][j] = MFMA16(av[i], bv[j], acc[i][j]);
        }
        __syncthreads();
    }
#pragma unroll
    for (int i = 0; i < 4; i++) {
        size_t r0 = m0 + wr + i * 16 + q16 * 4;
#pragma unroll
        for (int j = 0; j < 4; j++) {
            size_t c = n0 + wc + j * 16 + l16;
#pragma unroll
            for (int r = 0; r < 4; r++)
                C[(r0 + r) * N + c] = (h_t)acc[i][j][r];
        }
    }
}

// ---------------- V'' GEMM: +bias, transposed store Vt[b][d][n] -------------------
__global__ __launch_bounds__(256) void k_gemm_vt(const h_t* __restrict__ A,
                                                 const h_t* __restrict__ Bt,
                                                 const float* __restrict__ bo,
                                                 h_t* __restrict__ Vt,
                                                 int M, int N, int K) {
    __shared__ h_t As[128 * 64];
    __shared__ h_t Bs[128 * 64];
    int t = threadIdx.x, w = t >> 6, lane = t & 63;
    int q16 = lane >> 4, l16 = lane & 15;
    size_t m0 = (size_t)blockIdx.x * 128, n0 = (size_t)blockIdx.y * 128;
    int wr = (w >> 1) * 64, wc = (w & 1) * 64;
    f4 acc[4][4] = {};

    for (int k0 = 0; k0 < K; k0 += 64) {
#pragma unroll
        for (int j = 0; j < 4; j++) {
            int q = w * 4 + j;
            int row = q * 8 + (lane >> 3);
            int ks = (((lane & 7) ^ (row & 7)) << 3);
            gl2lds16(A + (m0 + row) * K + k0 + ks, &As[q * 512]);
            gl2lds16(Bt + (n0 + row) * K + k0 + ks, &Bs[q * 512]);
        }
        __syncthreads();
#pragma unroll
        for (int ks = 0; ks < 2; ks++) {
            h8 av[4], bv[4];
#pragma unroll
            for (int i = 0; i < 4; i++) {
                int row = wr + i * 16 + l16;
                int ch = ks * 4 + q16;
                av[i] = *(const h8*)&As[row * 64 + ((ch ^ (row & 7)) << 3)];
            }
#pragma unroll
            for (int j = 0; j < 4; j++) {
                int row = wc + j * 16 + l16;
                int ch = ks * 4 + q16;
                bv[j] = *(const h8*)&Bs[row * 64 + ((ch ^ (row & 7)) << 3)];
            }
#pragma unroll
            for (int i = 0; i < 4; i++)
#pragma unroll
                for (int j = 0; j < 4; j++)
                    acc[i][j] = MFMA16(av[i], bv[j], acc[i][j]);
        }
        __syncthreads();
    }
#pragma unroll
    for (int i = 0; i < 4; i++) {
        size_t gm = m0 + wr + i * 16 + q16 * 4;
        size_t b = gm >> 11;
        size_t n = gm & 2047;
#pragma unroll
        for (int j = 0; j < 4; j++) {
            size_t d = n0 + wc + j * 16 + l16;
            float bias = bo[d];
            h4 hv = {(h_t)(acc[i][j][0] + bias), (h_t)(acc[i][j][1] + bias),
                     (h_t)(acc[i][j][2] + bias), (h_t)(acc[i][j][3] + bias)};
            *(h4*)&Vt[(b * 512 + d) * 2048 + n] = hv;
        }
    }
}

// ---------------- flash attention, Q-tile 128, key-half split ----------------
// 256 blocks x 512 threads (8 waves = 8 row-bands of 16 Q-rows). QK^T is
// BARRIER-FREE: each wave loads its Q-band fragments and the shared K-tile
// fragments directly from global (frag = 8 contiguous halves at
// [row=l16][ks*32+q16*8]); latency hidden by 8-wave TLP, K re-read filtered
// by L1/L2. LDS holds only Ps (P cross-wave handoff) + arow; 2 barriers/kt.
__global__ __launch_bounds__(512, 2) void k_attn(const h_t* __restrict__ Qh,
                                                 const h_t* __restrict__ Kh,
                                                 const h_t* __restrict__ Vt,
                                                 h_t* __restrict__ Obar,
                                                 float2* __restrict__ Ml) {
    __shared__ h_t Ps[128 * 136];   // 34.8 KB
    __shared__ float arow[128];

    int t = threadIdx.x, w = t >> 6, lane = t & 63;
    int q16 = lane >> 4, l16 = lane & 15;
    int b = blockIdx.x & 7;
    int half = (blockIdx.x >> 3) & 1;
    int qt = blockIdx.x >> 4;
    int q0 = qt * 128;
    int kh0 = half * 1024;

    // lane-resolved fragment base pointers (row = l16, k-offset = q16*8)
    const h_t* Qw = Qh + ((size_t)b * 2048 + q0 + w * 16 + l16) * 1024 + q16 * 8;
    const h_t* Kl = Kh + ((size_t)b * 2048 + l16) * 1024 + q16 * 8;
    const h_t* Vbase = Vt + (size_t)b * 512 * 2048;

    f4 oacc[8][4] = {};
    float mrun[4] = {-1e30f, -1e30f, -1e30f, -1e30f};
    float lrun[4] = {0.f, 0.f, 0.f, 0.f};

    for (int kt = 0; kt < 8; kt++) {
        int kb = kh0 + kt * 128;
        const h_t* Kt = Kl + (size_t)kb * 1024;
        f4 sacc[8] = {};
        // ---- S = Q K^T over inner 1024, all operands straight from global ----
#pragma unroll 1
        for (int c = 0; c < 8; c++) {
#pragma unroll
            for (int ks = 0; ks < 4; ks++) {
                h8 qa = *(const h8*)(Qw + c * 128 + ks * 32);
#pragma unroll
                for (int j = 0; j < 8; j++) {
                    h8 bv = *(const h8*)(Kt + (size_t)j * 16 * 1024 + c * 128 + ks * 32);
                    sacc[j] = MFMA16(qa, bv, sacc[j]);
                }
            }
        }
        // ---- wave-local softmax over this kt's 128 keys ----
        float mt[4], st[4], beta[4];
#pragma unroll
        for (int r = 0; r < 4; r++) {
            float m = sacc[0][r];
#pragma unroll
            for (int j = 1; j < 8; j++) m = fmaxf(m, sacc[j][r]);
            mt[r] = m;
        }
#pragma unroll
        for (int m = 1; m <= 8; m <<= 1)
#pragma unroll
            for (int r = 0; r < 4; r++)
                mt[r] = fmaxf(mt[r], __shfl_xor(mt[r], m, 64));
#pragma unroll
        for (int r = 0; r < 4; r++) {
            float s = 0.f;
#pragma unroll
            for (int j = 0; j < 8; j++) {
                float e = __expf(sacc[j][r] - mt[r]);
                sacc[j][r] = e;
                s += e;
            }
            st[r] = s;
        }
#pragma unroll
        for (int m = 1; m <= 8; m <<= 1)
#pragma unroll
            for (int r = 0; r < 4; r++) st[r] += __shfl_xor(st[r], m, 64);
#pragma unroll
        for (int r = 0; r < 4; r++) {
            float mo = mrun[r];
            float mn = fmaxf(mo, mt[r]);
            float a = __expf(mo - mn);
            float bb = __expf(mt[r] - mn);
            lrun[r] = lrun[r] * a + st[r] * bb;
            mrun[r] = mn;
            beta[r] = bb;
            if (l16 == 0) arow[w * 16 + q16 * 4 + r] = a;
        }
        // P (rescaled) -> LDS, C-layout -> A-layout
#pragma unroll
        for (int j = 0; j < 8; j++)
#pragma unroll
            for (int r = 0; r < 4; r++)
                Ps[(w * 16 + q16 * 4 + r) * 136 + j * 16 + l16] =
                    (h_t)(sacc[j][r] * beta[r]);
        __syncthreads();
        // ---- rescale O, then O += P @ V'' (wave owns 64 of 512 d-cols) ----
#pragma unroll
        for (int i = 0; i < 8; i++) {
#pragma unroll
            for (int r = 0; r < 4; r++) {
                float a = arow[i * 16 + q16 * 4 + r];
#pragma unroll
                for (int j = 0; j < 4; j++) oacc[i][j][r] *= a;
            }
        }
#pragma unroll
        for (int ks = 0; ks < 4; ks++) {
            h8 vf[4];
#pragma unroll
            for (int j = 0; j < 4; j++) {
                int d = w * 64 + j * 16 + l16;
                vf[j] = *(const h8*)(Vbase + (size_t)d * 2048 + kb + ks * 32 + q16 * 8);
            }
#pragma unroll
            for (int i = 0; i < 8; i++) {
                h8 pf = *(const h8*)&Ps[(i * 16 + l16) * 136 + ks * 32 + q16 * 8];
#pragma unroll
                for (int j = 0; j < 4; j++)
                    oacc[i][j] = MFMA16(pf, vf[j], oacc[i][j]);
            }
        }
        __syncthreads();  // Ps/arow consumed before next kt rewrites them
    }
    // ---- epilogue: partial O (normalized by this half's l), m/l out ----
    if (l16 == 0) {
#pragma unroll
        for (int r = 0; r < 4; r++) arow[w * 16 + q16 * 4 + r] = lrun[r];
    }
    __syncthreads();
    size_t obase = (size_t)(half * 8 + b) * 2048 + q0;
#pragma unroll
    for (int i = 0; i < 8; i++) {
#pragma unroll
        for (int r = 0; r < 4; r++) {
            int row = i * 16 + q16 * 4 + r;
            float inv = 1.f / arow[row];
#pragma unroll
            for (int j = 0; j < 4; j++) {
                int d = w * 64 + j * 16 + l16;
                Obar[(obase + row) * 512 + d] = (h_t)(oacc[i][j][r] * inv);
            }
        }
    }
    if (l16 == 0) {
#pragma unroll
        for (int r = 0; r < 4; r++) {
            int row = w * 16 + q16 * 4 + r;
            Ml[obase + row] = make_float2(mrun[r], lrun[r]);
        }
    }
}

// ---------------- combine the two key-halves ----------------
__global__ __launch_bounds__(256) void k_comb(const h_t* __restrict__ Obar,
                                              const float2* __restrict__ Ml,
                                              float* __restrict__ Out) {
    int gid = blockIdx.x * 256 + threadIdx.x;  // 2,097,152 = 16384 rows x 128 d4
    int d4 = gid & 127;
    int rg = gid >> 7;  // b*2048 + row
    float2 ml0 = Ml[rg], ml1 = Ml[16384 + rg];
    float m = fmaxf(ml0.x, ml1.x);
    float w0 = ml0.y * __expf(ml0.x - m);
    float w1 = ml1.y * __expf(ml1.x - m);
    float inv = 1.f / (w0 + w1);
    w0 *= inv;
    w1 *= inv;
    h4 o0 = *(const h4*)&Obar[(size_t)rg * 512 + d4 * 4];
    h4 o1 = *(const h4*)&Obar[((size_t)16384 + rg) * 512 + d4 * 4];
    float4 o;
    o.x = w0 * (float)o0[0] + w1 * (float)o1[0];
    o.y = w0 * (float)o0[1] + w1 * (float)o1[1];
    o.z = w0 * (float)o0[2] + w1 * (float)o1[2];
    o.w = w0 * (float)o0[3] + w1 * (float)o1[3];
    *(float4*)&Out[(size_t)rg * 512 + d4 * 4] = o;
}

// ---------------- host ----------------
extern "C" void kernel_launch(void* const* d_in, const int* in_sizes, int n_in,
                              void* d_out, int out_size, void* d_ws, size_t ws_size,
                              hipStream_t stream) {
    const float* S1 = (const float*)d_in[0];
    const float* S2 = (const float*)d_in[1];
    const float* Wq = (const float*)d_in[2];
    const float* Wk = (const float*)d_in[3];
    const float* Wv = (const float*)d_in[4];
    const float* Wo = (const float*)d_in[5];
    const float* bo = (const float*)d_in[6];
    float* Out = (float*)d_out;

    char* ws = (char*)d_ws;
    h_t* S2h  = (h_t*)(ws);                 // 16 MB  (dead after Q-proj)
    h_t* S1h  = (h_t*)(ws + 16777216);      // 16 MB  (dead after Vt-proj)
    h_t* Wqt  = (h_t*)(ws + 33554432);      // 1 MB
    h_t* Wkt  = (h_t*)(ws + 34603008);      // 1 MB
    h_t* Wvot = (h_t*)(ws + 35651584);      // 0.5 MB (dead after Vt-proj)
    h_t* Qh   = (h_t*)(ws + 36175872);      // 32 MB
    h_t* Kh   = (h_t*)(ws + 69730304);      // 32 MB
    h_t* Vt   = (h_t*)(ws + 103284736);     // 16 MB -> end 120,061,952
    // aliases (dead regions reused):
    h_t* Wot  = (h_t*)(ws + 36175872);      // 1 MB  [512][1024] (pre-Qh)
    h_t* Wvh  = (h_t*)(ws + 37224448);      // 1 MB  [512][1024] (pre-Qh)
    h_t* Obar = (h_t*)(ws);                 // 32 MB [2][8][2048][512] over S2h+S1h
    float2* Ml = (float2*)(ws + 35651584);  // 256 KB [2][16384] over Wvot

    k_cast3<<<16896, 256, 0, stream>>>(S1, S2, Wv, S1h, S2h, Wvh);
    k_transpose3<<<dim3(32, 32, 3), 256, 0, stream>>>(Wq, Wk, Wo, Wqt, Wkt, Wot);
    // Wvot[d][c] = sum_e Wot[d][e] * Wvh[c][e] = (Wv @ Wo)^T
    k_gemm<<<dim3(4, 4), 256, 0, stream>>>(Wot, Wvh, Wvot, 512, 512, 1024);
    k_gemm<<<dim3(128, 8), 256, 0, stream>>>(S2h, Wqt, Qh, 16384, 1024, 512);
    k_gemm<<<dim3(128, 8), 256, 0, stream>>>(S1h, Wkt, Kh, 16384, 1024, 512);
    k_gemm_vt<<<dim3(128, 4), 256, 0, stream>>>(S1h, Wvot, bo, Vt, 16384, 512, 512);
    k_attn<<<256, 512, 0, stream>>>(Qh, Kh, Vt, Obar, Ml);
    k_comb<<<8192, 256, 0, stream>>>(Obar, Ml, Out);
}

// Round 3
// 417.467 us; speedup vs baseline: 1.8575x; 1.8575x over previous
//
#include <hip/hip_runtime.h>

// CrossAttention: out = softmax((S2 Wq)(S1 Wk)^T) (S1 Wv) Wo + bo
// Refactored: Wvo = Wv@Wo;  V'' = S1@Wvo + bo;  out = softmax(QK^T) @ V''
// R9: R6's proven structure (512 thr, Q-tile 128, key-half split, LDS-staged
// Q/K, vf[4] PV) + T3/T4 counted-vmcnt double-buffer pipeline on the QK^T
// staging: per chunk, stage NEXT chunk into buf[cur^1], s_waitcnt vmcnt(8)
// (current chunk only; next stays in flight across the barrier), raw
// s_barrier, MFMA, raw s_barrier. Next-kt chunk0 prefetched at c=7 hides
// under softmax+PV. Ps aliases buf1; prefetch targets buf0 (disjoint).
// LDS 128.5 KB, 1 block/CU (register-capped at 8 waves/CU regardless).

typedef _Float16 h_t;
typedef _Float16 h8 __attribute__((ext_vector_type(8)));
typedef _Float16 h4 __attribute__((ext_vector_type(4)));
typedef float f4 __attribute__((ext_vector_type(4)));

#define MFMA16(a, b, c) __builtin_amdgcn_mfma_f32_16x16x32_f16(a, b, c, 0, 0, 0)

typedef const __attribute__((address_space(1))) void* gas_t;
typedef __attribute__((address_space(3))) void* las_t;

__device__ __forceinline__ void gl2lds16(const void* g, void* l) {
    __builtin_amdgcn_global_load_lds((gas_t)g, (las_t)l, 16, 0, 0);
}

// ---------------- merged cast fp32 -> fp16: S1, S2, Wv ----------------
__global__ __launch_bounds__(256) void k_cast3(const float* __restrict__ S1,
                                               const float* __restrict__ S2,
                                               const float* __restrict__ Wv,
                                               h_t* __restrict__ S1h,
                                               h_t* __restrict__ S2h,
                                               h_t* __restrict__ Wvh) {
    long i = (long)blockIdx.x * 256 + threadIdx.x;  // f4 index
    const long n = 2097152;                          // S1/S2 f4 count
    const float* src;
    h_t* dst;
    long off;
    if (i < n) { src = S1; dst = S1h; off = i; }
    else if (i < 2 * n) { src = S2; dst = S2h; off = i - n; }
    else { src = Wv; dst = Wvh; off = i - 2 * n; }
    float4 v = *((const float4*)src + off);
    h4 h = {(h_t)v.x, (h_t)v.y, (h_t)v.z, (h_t)v.w};
    *((h4*)dst + off) = h;
}

// ---------------- merged transpose+cast: Wq, Wk, Wo -> [N][K] f16 ----------------
__global__ __launch_bounds__(256) void k_transpose3(const float* __restrict__ Wq,
                                                    const float* __restrict__ Wk,
                                                    const float* __restrict__ Wo,
                                                    h_t* __restrict__ Wqt,
                                                    h_t* __restrict__ Wkt,
                                                    h_t* __restrict__ Wot) {
    const float* in;
    h_t* out;
    int K, N;
    if (blockIdx.z == 0) { in = Wq; out = Wqt; K = 512; N = 1024; }
    else if (blockIdx.z == 1) { in = Wk; out = Wkt; K = 512; N = 1024; }
    else { in = Wo; out = Wot; K = 1024; N = 512; }
    int kb = blockIdx.y * 32, nb = blockIdx.x * 32;
    if (kb >= K || nb >= N) return;
    __shared__ float tile[32][33];
    int x = threadIdx.x & 31, y = threadIdx.x >> 5;
#pragma unroll
    for (int j = 0; j < 4; j++)
        tile[y + j * 8][x] = in[(size_t)(kb + y + j * 8) * N + nb + x];
    __syncthreads();
#pragma unroll
    for (int j = 0; j < 4; j++)
        out[(size_t)(nb + y + j * 8) * K + kb + x] = (h_t)tile[x][y + j * 8];
}

// ---------------- m97-style NT GEMM: C[M][N] f16 = A[M][K] x Bt[N][K]^T ------------
__global__ __launch_bounds__(256) void k_gemm(const h_t* __restrict__ A,
                                              const h_t* __restrict__ Bt,
                                              h_t* __restrict__ C,
                                              int M, int N, int K) {
    __shared__ h_t As[128 * 64];
    __shared__ h_t Bs[128 * 64];
    int t = threadIdx.x, w = t >> 6, lane = t & 63;
    int q16 = lane >> 4, l16 = lane & 15;
    size_t m0 = (size_t)blockIdx.x * 128, n0 = (size_t)blockIdx.y * 128;
    int wr = (w >> 1) * 64, wc = (w & 1) * 64;
    f4 acc[4][4] = {};

    for (int k0 = 0; k0 < K; k0 += 64) {
#pragma unroll
        for (int j = 0; j < 4; j++) {
            int q = w * 4 + j;
            int row = q * 8 + (lane >> 3);
            int ks = (((lane & 7) ^ (row & 7)) << 3);
            gl2lds16(A + (m0 + row) * K + k0 + ks, &As[q * 512]);
            gl2lds16(Bt + (n0 + row) * K + k0 + ks, &Bs[q * 512]);
        }
        __syncthreads();
#pragma unroll
        for (int ks = 0; ks < 2; ks++) {
            h8 av[4], bv[4];
#pragma unroll
            for (int i = 0; i < 4; i++) {
                int row = wr + i * 16 + l16;
                int ch = ks * 4 + q16;
                av[i] = *(const h8*)&As[row * 64 + ((ch ^ (row & 7)) << 3)];
            }
#pragma unroll
            for (int j = 0; j < 4; j++) {
                int row = wc + j * 16 + l16;
                int ch = ks * 4 + q16;
                bv[j] = *(const h8*)&Bs[row * 64 + ((ch ^ (row & 7)) << 3)];
            }
#pragma unroll
            for (int i = 0; i < 4; i++)
#pragma unroll
                for (int j = 0; j < 4; j++)
                    acc[i][j] = MFMA16(av[i], bv[j], acc[i][j]);
        }
        __syncthreads();
    }
#pragma unroll
    for (int i = 0; i < 4; i++) {
        size_t r0 = m0 + wr + i * 16 + q16 * 4;
#pragma unroll
        for (int j = 0; j < 4; j++) {
            size_t c = n0 + wc + j * 16 + l16;
#pragma unroll
            for (int r = 0; r < 4; r++)
                C[(r0 + r) * N + c] = (h_t)acc[i][j][r];
        }
    }
}

// ---------------- V'' GEMM: +bias, transposed store Vt[b][d][n] -------------------
__global__ __launch_bounds__(256) void k_gemm_vt(const h_t* __restrict__ A,
                                                 const h_t* __restrict__ Bt,
                                                 const float* __restrict__ bo,
                                                 h_t* __restrict__ Vt,
                                                 int M, int N, int K) {
    __shared__ h_t As[128 * 64];
    __shared__ h_t Bs[128 * 64];
    int t = threadIdx.x, w = t >> 6, lane = t & 63;
    int q16 = lane >> 4, l16 = lane & 15;
    size_t m0 = (size_t)blockIdx.x * 128, n0 = (size_t)blockIdx.y * 128;
    int wr = (w >> 1) * 64, wc = (w & 1) * 64;
    f4 acc[4][4] = {};

    for (int k0 = 0; k0 < K; k0 += 64) {
#pragma unroll
        for (int j = 0; j < 4; j++) {
            int q = w * 4 + j;
            int row = q * 8 + (lane >> 3);
            int ks = (((lane & 7) ^ (row & 7)) << 3);
            gl2lds16(A + (m0 + row) * K + k0 + ks, &As[q * 512]);
            gl2lds16(Bt + (n0 + row) * K + k0 + ks, &Bs[q * 512]);
        }
        __syncthreads();
#pragma unroll
        for (int ks = 0; ks < 2; ks++) {
            h8 av[4], bv[4];
#pragma unroll
            for (int i = 0; i < 4; i++) {
                int row = wr + i * 16 + l16;
                int ch = ks * 4 + q16;
                av[i] = *(const h8*)&As[row * 64 + ((ch ^ (row & 7)) << 3)];
            }
#pragma unroll
            for (int j = 0; j < 4; j++) {
                int row = wc + j * 16 + l16;
                int ch = ks * 4 + q16;
                bv[j] = *(const h8*)&Bs[row * 64 + ((ch ^ (row & 7)) << 3)];
            }
#pragma unroll
            for (int i = 0; i < 4; i++)
#pragma unroll
                for (int j = 0; j < 4; j++)
                    acc[i][j] = MFMA16(av[i], bv[j], acc[i][j]);
        }
        __syncthreads();
    }
#pragma unroll
    for (int i = 0; i < 4; i++) {
        size_t gm = m0 + wr + i * 16 + q16 * 4;
        size_t b = gm >> 11;
        size_t n = gm & 2047;
#pragma unroll
        for (int j = 0; j < 4; j++) {
            size_t d = n0 + wc + j * 16 + l16;
            float bias = bo[d];
            h4 hv = {(h_t)(acc[i][j][0] + bias), (h_t)(acc[i][j][1] + bias),
                     (h_t)(acc[i][j][2] + bias), (h_t)(acc[i][j][3] + bias)};
            *(h4*)&Vt[(b * 512 + d) * 2048 + n] = hv;
        }
    }
}

// ---------------- flash attention, Q-tile 128, key-half split ----------------
// 256 blocks x 512 threads (8 waves = 8 row-bands of 16 Q-rows). QK^T staging
// is double-buffered with counted vmcnt: stage chunk c+1 into buf[cur^1],
// wait vmcnt(8) (chunk c's 8 gl2lds only), raw barrier, MFMA, raw barrier.
// Next-kt chunk0 prefetched at c=7, hidden under softmax+PV. Ps aliases buf1.
__global__ __launch_bounds__(512, 2) void k_attn(const h_t* __restrict__ Qh,
                                                 const h_t* __restrict__ Kh,
                                                 const h_t* __restrict__ Vt,
                                                 h_t* __restrict__ Obar,
                                                 float2* __restrict__ Ml) {
    __shared__ h_t smem[2][32768];  // 2 x 64KB: buf[i] = Qs(16384) + Ks(16384)
    __shared__ float arow[128];
    h_t* Ps = &smem[1][0];          // 17408 halves, aliases buf1 (PV phase only)

    int t = threadIdx.x, w = t >> 6, lane = t & 63;
    int q16 = lane >> 4, l16 = lane & 15;
    int b = blockIdx.x & 7;
    int half = (blockIdx.x >> 3) & 1;
    int qt = blockIdx.x >> 4;
    int q0 = qt * 128;
    int kh0 = half * 1024;
    int rof = lane >> 4, g = lane & 15;

    const h_t* Qbase = Qh + ((size_t)b * 2048 + q0) * 1024;
    const h_t* Kbase = Kh + (size_t)b * 2048 * 1024;
    const h_t* Vbase = Vt + (size_t)b * 512 * 2048;

    // stage chunk (kt_, c_) of Q and K into buffer bsel (8 gl2lds per wave)
    auto STAGE = [&](int kt_, int c_, int bsel) {
#pragma unroll
        for (int j = 0; j < 4; j++) {
            int row = w * 16 + j * 4 + rof;
            int gsrc = g ^ (row & 7);
            gl2lds16(Qbase + (size_t)row * 1024 + c_ * 128 + gsrc * 8,
                     &smem[bsel][(w * 16 + j * 4) * 128]);
        }
        int kb_ = kh0 + kt_ * 128;
#pragma unroll
        for (int j = 0; j < 4; j++) {
            int row = w * 16 + j * 4 + rof;
            int gsrc = g ^ (row & 7);
            gl2lds16(Kbase + (size_t)(kb_ + row) * 1024 + c_ * 128 + gsrc * 8,
                     &smem[bsel][16384 + (w * 16 + j * 4) * 128]);
        }
    };

    f4 oacc[8][4] = {};
    float mrun[4] = {-1e30f, -1e30f, -1e30f, -1e30f};
    float lrun[4] = {0.f, 0.f, 0.f, 0.f};

    STAGE(0, 0, 0);  // prologue
    int cur = 0;

#pragma unroll 1
    for (int kt = 0; kt < 8; kt++) {
        int kb = kh0 + kt * 128;
        f4 sacc[8] = {};
        // ---- S = Q K^T over inner 1024 in 8 chunks of 128, pipelined ----
#pragma unroll 1
        for (int c = 0; c < 8; c++) {
            if (!(kt == 7 && c == 7)) {
                // stage next chunk (c+1, or next kt's chunk 0) into other buffer
                int nkt = (c == 7) ? kt + 1 : kt;
                int nc = (c == 7) ? 0 : c + 1;
                STAGE(nkt, nc, cur ^ 1);
                // wait only current chunk's 8 loads; next chunk's stay in flight
                asm volatile("s_waitcnt vmcnt(8)" ::: "memory");
            } else {
                asm volatile("s_waitcnt vmcnt(0)" ::: "memory");
            }
            __builtin_amdgcn_s_barrier();   // all waves' chunk-c data landed
            asm volatile("" ::: "memory");
            const h_t* Qs = &smem[cur][0];
            const h_t* Ks = &smem[cur][16384];
            int ar = w * 16 + l16;
#pragma unroll
            for (int ks = 0; ks < 4; ks++) {
                h8 qa = *(const h8*)&Qs[ar * 128 + (((ks * 4 + q16) ^ (ar & 7)) << 3)];
#pragma unroll
                for (int j = 0; j < 8; j++) {
                    int kr = j * 16 + l16;
                    h8 bv = *(const h8*)&Ks[kr * 128 + (((ks * 4 + q16) ^ (kr & 7)) << 3)];
                    sacc[j] = MFMA16(qa, bv, sacc[j]);
                }
            }
            asm volatile("" ::: "memory");
            __builtin_amdgcn_s_barrier();   // all waves done reading buf[cur]
            cur ^= 1;
        }
        // ---- wave-local softmax over this kt's 128 keys ----
        float mt[4], st[4], beta[4];
#pragma unroll
        for (int r = 0; r < 4; r++) {
            float m = sacc[0][r];
#pragma unroll
            for (int j = 1; j < 8; j++) m = fmaxf(m, sacc[j][r]);
            mt[r] = m;
        }
#pragma unroll
        for (int m = 1; m <= 8; m <<= 1)
#pragma unroll
            for (int r = 0; r < 4; r++)
                mt[r] = fmaxf(mt[r], __shfl_xor(mt[r], m, 64));
#pragma unroll
        for (int r = 0; r < 4; r++) {
            float s = 0.f;
#pragma unroll
            for (int j = 0; j < 8; j++) {
                float e = __expf(sacc[j][r] - mt[r]);
                sacc[j][r] = e;
                s += e;
            }
            st[r] = s;
        }
#pragma unroll
        for (int m = 1; m <= 8; m <<= 1)
#pragma unroll
            for (int r = 0; r < 4; r++) st[r] += __shfl_xor(st[r], m, 64);
#pragma unroll
        for (int r = 0; r < 4; r++) {
            float mo = mrun[r];
            float mn = fmaxf(mo, mt[r]);
            float a = __expf(mo - mn);
            float bb = __expf(mt[r] - mn);
            lrun[r] = lrun[r] * a + st[r] * bb;
            mrun[r] = mn;
            beta[r] = bb;
            if (l16 == 0) arow[w * 16 + q16 * 4 + r] = a;
        }
        // P (rescaled) -> LDS (aliases buf1; chunk 7 fully consumed), C->A layout
#pragma unroll
        for (int j = 0; j < 8; j++)
#pragma unroll
            for (int r = 0; r < 4; r++)
                Ps[(w * 16 + q16 * 4 + r) * 136 + j * 16 + l16] =
                    (h_t)(sacc[j][r] * beta[r]);
        asm volatile("s_waitcnt lgkmcnt(0)" ::: "memory");
        __builtin_amdgcn_s_barrier();   // Ps + arow visible to all waves
        asm volatile("" ::: "memory");
        // ---- rescale O, then O += P @ V'' (wave owns 64 of 512 d-cols) ----
#pragma unroll
        for (int i = 0; i < 8; i++) {
#pragma unroll
            for (int r = 0; r < 4; r++) {
                float a = arow[i * 16 + q16 * 4 + r];
#pragma unroll
                for (int j = 0; j < 4; j++) oacc[i][j][r] *= a;
            }
        }
#pragma unroll
        for (int ks = 0; ks < 4; ks++) {
            h8 vf[4];
#pragma unroll
            for (int j = 0; j < 4; j++) {
                int d = w * 64 + j * 16 + l16;
                vf[j] = *(const h8*)(Vbase + (size_t)d * 2048 + kb + ks * 32 + q16 * 8);
            }
#pragma unroll
            for (int i = 0; i < 8; i++) {
                h8 pf = *(const h8*)&Ps[(i * 16 + l16) * 136 + ks * 32 + q16 * 8];
#pragma unroll
                for (int j = 0; j < 4; j++)
                    oacc[i][j] = MFMA16(pf, vf[j], oacc[i][j]);
            }
        }
        asm volatile("s_waitcnt lgkmcnt(0)" ::: "memory");
        __builtin_amdgcn_s_barrier();   // Ps/arow consumed; buf1 free for restage
        asm volatile("" ::: "memory");
    }
    // ---- epilogue: partial O (normalized by this half's l), m/l out ----
    if (l16 == 0) {
#pragma unroll
        for (int r = 0; r < 4; r++) arow[w * 16 + q16 * 4 + r] = lrun[r];
    }
    __syncthreads();
    size_t obase = (size_t)(half * 8 + b) * 2048 + q0;
#pragma unroll
    for (int i = 0; i < 8; i++) {
#pragma unroll
        for (int r = 0; r < 4; r++) {
            int row = i * 16 + q16 * 4 + r;
            float inv = 1.f / arow[row];
#pragma unroll
            for (int j = 0; j < 4; j++) {
                int d = w * 64 + j * 16 + l16;
                Obar[(obase + row) * 512 + d] = (h_t)(oacc[i][j][r] * inv);
            }
        }
    }
    if (l16 == 0) {
#pragma unroll
        for (int r = 0; r < 4; r++) {
            int row = w * 16 + q16 * 4 + r;
            Ml[obase + row] = make_float2(mrun[r], lrun[r]);
        }
    }
}

// ---------------- combine the two key-halves ----------------
__global__ __launch_bounds__(256) void k_comb(const h_t* __restrict__ Obar,
                                              const float2* __restrict__ Ml,
                                              float* __restrict__ Out) {
    int gid = blockIdx.x * 256 + threadIdx.x;  // 2,097,152 = 16384 rows x 128 d4
    int d4 = gid & 127;
    int rg = gid >> 7;  // b*2048 + row
    float2 ml0 = Ml[rg], ml1 = Ml[16384 + rg];
    float m = fmaxf(ml0.x, ml1.x);
    float w0 = ml0.y * __expf(ml0.x - m);
    float w1 = ml1.y * __expf(ml1.x - m);
    float inv = 1.f / (w0 + w1);
    w0 *= inv;
    w1 *= inv;
    h4 o0 = *(const h4*)&Obar[(size_t)rg * 512 + d4 * 4];
    h4 o1 = *(const h4*)&Obar[((size_t)16384 + rg) * 512 + d4 * 4];
    float4 o;
    o.x = w0 * (float)o0[0] + w1 * (float)o1[0];
    o.y = w0 * (float)o0[1] + w1 * (float)o1[1];
    o.z = w0 * (float)o0[2] + w1 * (float)o1[2];
    o.w = w0 * (float)o0[3] + w1 * (float)o1[3];
    *(float4*)&Out[(size_t)rg * 512 + d4 * 4] = o;
}

// ---------------- host ----------------
extern "C" void kernel_launch(void* const* d_in, const int* in_sizes, int n_in,
                              void* d_out, int out_size, void* d_ws, size_t ws_size,
                              hipStream_t stream) {
    const float* S1 = (const float*)d_in[0];
    const float* S2 = (const float*)d_in[1];
    const float* Wq = (const float*)d_in[2];
    const float* Wk = (const float*)d_in[3];
    const float* Wv = (const float*)d_in[4];
    const float* Wo = (const float*)d_in[5];
    const float* bo = (const float*)d_in[6];
    float* Out = (float*)d_out;

    char* ws = (char*)d_ws;
    h_t* S2h  = (h_t*)(ws);                 // 16 MB  (dead after Q-proj)
    h_t* S1h  = (h_t*)(ws + 16777216);      // 16 MB  (dead after Vt-proj)
    h_t* Wqt  = (h_t*)(ws + 33554432);      // 1 MB
    h_t* Wkt  = (h_t*)(ws + 34603008);      // 1 MB
    h_t* Wvot = (h_t*)(ws + 35651584);      // 0.5 MB (dead after Vt-proj)
    h_t* Qh   = (h_t*)(ws + 36175872);      // 32 MB
    h_t* Kh   = (h_t*)(ws + 69730304);      // 32 MB
    h_t* Vt   = (h_t*)(ws + 103284736);     // 16 MB -> end 120,061,952
    // aliases (dead regions reused):
    h_t* Wot  = (h_t*)(ws + 36175872);      // 1 MB  [512][1024] (pre-Qh)
    h_t* Wvh  = (h_t*)(ws + 37224448);      // 1 MB  [512][1024] (pre-Qh)
    h_t* Obar = (h_t*)(ws);                 // 32 MB [2][8][2048][512] over S2h+S1h
    float2* Ml = (float2*)(ws + 35651584);  // 256 KB [2][16384] over Wvot

    k_cast3<<<16896, 256, 0, stream>>>(S1, S2, Wv, S1h, S2h, Wvh);
    k_transpose3<<<dim3(32, 32, 3), 256, 0, stream>>>(Wq, Wk, Wo, Wqt, Wkt, Wot);
    // Wvot[d][c] = sum_e Wot[d][e] * Wvh[c][e] = (Wv @ Wo)^T
    k_gemm<<<dim3(4, 4), 256, 0, stream>>>(Wot, Wvh, Wvot, 512, 512, 1024);
    k_gemm<<<dim3(128, 8), 256, 0, stream>>>(S2h, Wqt, Qh, 16384, 1024, 512);
    k_gemm<<<dim3(128, 8), 256, 0, stream>>>(S1h, Wkt, Kh, 16384, 1024, 512);
    k_gemm_vt<<<dim3(128, 4), 256, 0, stream>>>(S1h, Wvot, bo, Vt, 16384, 512, 512);
    k_attn<<<256, 512, 0, stream>>>(Qh, Kh, Vt, Obar, Ml);
    k_comb<<<8192, 256, 0, stream>>>(Obar, Ml, Out);
}